// Round 12
// baseline (251.948 us; speedup 1.0000x reference)
//
#include <hip/hip_runtime.h>
#include <math.h>

#define Dd 256
#define Nn 4096
#define Bb 4
#define BQ 128      // q rows per attn block (8 waves x 16 in S phase)
#define BK 128      // kv rows per tile (one barrier-triple per 128 MFMA/wave)
#define SPLIT 2     // KV splits -> grid exactly 256 blocks = 1 round

typedef _Float16 f16;
typedef _Float16 half8 __attribute__((ext_vector_type(8)));
typedef _Float16 half4 __attribute__((ext_vector_type(4)));
typedef float f32x4 __attribute__((ext_vector_type(4)));

#define LOG2E 1.4426950408889634f

// DPP row_ror butterfly over 16-lane rows (VALU pipe, not LDS)
template <int CTRL>
__device__ __forceinline__ float dppf(float x) {
    int r = __builtin_amdgcn_update_dpp(0, __builtin_bit_cast(int, x),
                                        CTRL, 0xF, 0xF, false);
    return __builtin_bit_cast(float, r);
}
__device__ __forceinline__ float red16_max(float x) {
    x = fmaxf(x, dppf<0x128>(x));
    x = fmaxf(x, dppf<0x124>(x));
    x = fmaxf(x, dppf<0x122>(x));
    x = fmaxf(x, dppf<0x121>(x));
    return x;
}
__device__ __forceinline__ float red16_sum(float x) {
    x += dppf<0x128>(x); x += dppf<0x124>(x);
    x += dppf<0x122>(x); x += dppf<0x121>(x);
    return x;
}

// ---------------------------------------------------------------------------
// Kernel 0: W transpose+cast.  Wt[which][d'][d] = (f16) W[d][d']
// ---------------------------------------------------------------------------
__global__ __launch_bounds__(256) void wtrans(
    const float* __restrict__ Wq, const float* __restrict__ Wk,
    const float* __restrict__ Wv, f16* __restrict__ Wt)
{
    __shared__ float ld[64][65];
    const int which = blockIdx.y;
    const float* W = which == 0 ? Wq : (which == 1 ? Wk : Wv);
    const int tr = (blockIdx.x >> 2) * 64;
    const int tc = (blockIdx.x & 3) * 64;
    const int t = threadIdx.x;
    #pragma unroll
    for (int i = 0; i < 16; ++i) {
        int u = t + i * 256, r = u >> 6, c = u & 63;
        ld[r][c] = W[(size_t)(tr + r) * Dd + tc + c];
    }
    __syncthreads();
    f16* Wo = Wt + (size_t)which * Dd * Dd;
    #pragma unroll
    for (int i = 0; i < 16; ++i) {
        int u = t + i * 256, cp = u >> 6, rp = u & 63;
        Wo[(size_t)(tc + cp) * Dd + tr + rp] = (f16)ld[rp][cp];
    }
}

// ---------------------------------------------------------------------------
// Kernel 1: QKV projection via MFMA.
// R12: W B-fragments read DIRECTLY from global Wt (L2-resident: 128 KB
// shared by all 768 blocks). Deletes the Wls LDS buffer and the 16 c-loop
// barriers (the R10/R11 attn lesson applied here). Fragment addresses are
// byte-identical to the old LDS reads -> bit-identical results.
// Only barrier left: xT staging.
// ---------------------------------------------------------------------------
__global__ __launch_bounds__(256, 2) void qkv_mfma(
    const float* __restrict__ x, const f16* __restrict__ Wt,
    const float* __restrict__ bq, const float* __restrict__ bk,
    const float* __restrict__ bv,
    f16* __restrict__ Qh, f16* __restrict__ Kh, f16* __restrict__ Vth)
{
    __shared__ f16 xT[64][264];
    __shared__ float bs[256];
    const int t = threadIdx.x;
    const int wave = t >> 6, lane = t & 63, quad = lane >> 4, l15 = lane & 15;
    const int n0 = blockIdx.x * 64;
    const int b = blockIdx.y, which = blockIdx.z;
    const float* bias = which == 0 ? bq : (which == 1 ? bk : bv);
    bs[t] = bias[t];

    const float* xb = x + (size_t)b * Dd * Nn;
    #pragma unroll
    for (int i = 0; i < 16; ++i) {
        int u = t + i * 256, d = u >> 4, nq = (u & 15) * 4;
        float4 v4 = *(const float4*)&xb[(size_t)d * Nn + n0 + nq];
        xT[nq + 0][d] = (f16)v4.x; xT[nq + 1][d] = (f16)v4.y;
        xT[nq + 2][d] = (f16)v4.z; xT[nq + 3][d] = (f16)v4.w;
    }
    __syncthreads();

    half8 a[8];
    #pragma unroll
    for (int c = 0; c < 8; ++c)
        a[c] = *(const half8*)&xT[16 * wave + l15][c * 32 + quad * 8];

    f32x4 acc[16];
    #pragma unroll
    for (int dt = 0; dt < 16; ++dt) acc[dt] = (f32x4){0.f, 0.f, 0.f, 0.f};

    // B-frag base: row d' = dt*16 + l15, cols c*32 + quad*8 .. +8
    const f16* Wb = Wt + (size_t)which * Dd * Dd + (size_t)l15 * Dd + quad * 8;
    #pragma unroll
    for (int c = 0; c < 8; ++c) {
        #pragma unroll
        for (int dt = 0; dt < 16; ++dt) {
            half8 bfr = *(const half8*)(Wb + (size_t)dt * 16 * Dd + c * 32);
            acc[dt] = __builtin_amdgcn_mfma_f32_16x16x32_f16(a[c], bfr, acc[dt], 0, 0, 0);
        }
    }

    const int nrow = n0 + 16 * wave + quad * 4;
    if (which < 2) {
        f16* O = (which == 0 ? Qh : Kh) + ((size_t)b * Nn + nrow) * Dd;
        #pragma unroll
        for (int dt = 0; dt < 16; ++dt) {
            int col = dt * 16 + l15;
            float bvv = bs[col];
            #pragma unroll
            for (int r = 0; r < 4; ++r)
                O[(size_t)r * Dd + col] = (f16)(acc[dt][r] + bvv);
        }
    } else {
        f16* O = Vth + (size_t)b * Dd * Nn;
        #pragma unroll
        for (int dt = 0; dt < 16; ++dt) {
            int col = dt * 16 + l15;
            float bvv = bs[col];
            half4 o;
            #pragma unroll
            for (int r = 0; r < 4; ++r) o[r] = (f16)(acc[dt][r] + bvv);
            *(half4*)&O[(size_t)col * Nn + nrow] = o;
        }
    }
}

// ---------------------------------------------------------------------------
// Kernel 2: MFMA flash attention (unchanged from R11 winner). BK=128:
// 3 barriers per 128 MFMA/wave (16 iterations). BQ=128, 512 threads,
// SPLIT=2 -> grid 256 blocks = 1 round. Wave-split-D PV (32 d-cols/wave).
// ---------------------------------------------------------------------------
__global__ __launch_bounds__(512, 2) void attn_mfma(
    const f16* __restrict__ Qh, const f16* __restrict__ Kh,
    const f16* __restrict__ Vth, f16* __restrict__ Opart,
    float* __restrict__ mpart, float* __restrict__ lpart)
{
    __shared__ f16 Ks[BK][264];       // 67584 B  K[kv][d], pad 8
    __shared__ f16 Ps[8][16][136];    // 34816 B  P[qb][q][kv 0..127], pad 8
    __shared__ float alpha_s[8][16];  //   512 B
    __shared__ float l_sh[8][16];     //   512 B

    const int t    = threadIdx.x;
    const int wave = t >> 6, lane = t & 63;
    const int quad = lane >> 4, l15 = lane & 15;
    const int b    = blockIdx.y;
    const int s    = blockIdx.z;
    const int q0   = blockIdx.x * BQ;
    const int qw   = q0 + wave * 16;       // this wave's S-phase q rows
    const int kv0  = s * (Nn / SPLIT);

    // Q A-fragments, pre-scaled by log2(e)
    half8 qf[8];
    const f16* Qrow = Qh + ((size_t)b * Nn + qw + l15) * Dd + quad * 8;
    #pragma unroll
    for (int c = 0; c < 8; ++c) {
        qf[c] = *(const half8*)(Qrow + c * 32);
        qf[c] = qf[c] * (f16)LOG2E;
    }

    // acc[qb*2+dt]: q-block qb (0..7), d-cols 32*wave + dt*16 + l15 (dt 0..1)
    f32x4 acc[16];
    #pragma unroll
    for (int n = 0; n < 16; ++n) acc[n] = (f32x4){0.f, 0.f, 0.f, 0.f};
    f32x4 m4 = {-1e30f, -1e30f, -1e30f, -1e30f};
    f32x4 l4 = {0.f, 0.f, 0.f, 0.f};

    const f16* Kb   = Kh + (size_t)b * Nn * Dd;
    const f16* Vrow = Vth + (size_t)b * Dd * Nn
                    + (size_t)(wave * 32 + l15) * Nn + quad * 8;

    for (int k0 = kv0; k0 < kv0 + Nn / SPLIT; k0 += BK) {
        // Iter-top V loads: 2 d-tiles x 4 kv-quarters (full 128B V lines)
        half8 vbf[2][4];   // [dt][kv quarter]
        #pragma unroll
        for (int dt = 0; dt < 2; ++dt) {
            #pragma unroll
            for (int cbb = 0; cbb < 4; ++cbb)
                vbf[dt][cbb] = *(const half8*)(Vrow + (size_t)dt * 16 * Nn + k0 + cbb * 32);
        }

        __syncthreads();   // A: prior readers of Ks/Ps done

        // Stage K tile: 128 rows x 512 B = 64 KB; 8 x b128 per thread
        #pragma unroll
        for (int i = 0; i < 8; ++i) {
            int u = t + i * 512;
            int r = u >> 5, c = u & 31;
            *(half8*)&Ks[r][c * 8] =
                *(const half8*)(Kb + (size_t)(k0 + r) * Dd + c * 8);
        }
        __syncthreads();   // B: K visible

        // S = Q K^T (log2 domain), eight 16x16 col-blocks (kv 0..127)
        f32x4 S[8];
        #pragma unroll
        for (int cb = 0; cb < 8; ++cb) S[cb] = (f32x4){0.f, 0.f, 0.f, 0.f};
        #pragma unroll
        for (int c = 0; c < 8; ++c) {
            #pragma unroll
            for (int cb = 0; cb < 8; ++cb) {
                half8 kb = *(const half8*)&Ks[cb * 16 + l15][c * 32 + quad * 8];
                S[cb] = __builtin_amdgcn_mfma_f32_16x16x32_f16(qf[c], kb, S[cb], 0, 0, 0);
            }
        }

        // Online softmax (exp2 domain), DPP reductions over 16 lanes
        f32x4 tmax = S[0];
        #pragma unroll
        for (int cb = 1; cb < 8; ++cb) {
            tmax.x = fmaxf(tmax.x, S[cb].x); tmax.y = fmaxf(tmax.y, S[cb].y);
            tmax.z = fmaxf(tmax.z, S[cb].z); tmax.w = fmaxf(tmax.w, S[cb].w);
        }
        tmax.x = red16_max(tmax.x); tmax.y = red16_max(tmax.y);
        tmax.z = red16_max(tmax.z); tmax.w = red16_max(tmax.w);
        f32x4 newm;
        newm.x = fmaxf(m4.x, tmax.x); newm.y = fmaxf(m4.y, tmax.y);
        newm.z = fmaxf(m4.z, tmax.z); newm.w = fmaxf(m4.w, tmax.w);
        f32x4 al;
        al.x = __builtin_amdgcn_exp2f(m4.x - newm.x);
        al.y = __builtin_amdgcn_exp2f(m4.y - newm.y);
        al.z = __builtin_amdgcn_exp2f(m4.z - newm.z);
        al.w = __builtin_amdgcn_exp2f(m4.w - newm.w);
        f32x4 P[8];
        #pragma unroll
        for (int cb = 0; cb < 8; ++cb) {
            P[cb].x = __builtin_amdgcn_exp2f(S[cb].x - newm.x);
            P[cb].y = __builtin_amdgcn_exp2f(S[cb].y - newm.y);
            P[cb].z = __builtin_amdgcn_exp2f(S[cb].z - newm.z);
            P[cb].w = __builtin_amdgcn_exp2f(S[cb].w - newm.w);
        }
        f32x4 rsum = P[0];
        #pragma unroll
        for (int cb = 1; cb < 8; ++cb) rsum += P[cb];
        rsum.x = red16_sum(rsum.x); rsum.y = red16_sum(rsum.y);
        rsum.z = red16_sum(rsum.z); rsum.w = red16_sum(rsum.w);
        l4 = l4 * al + rsum;
        m4 = newm;

        // Publish P (f16) and alpha
        const int pr = quad * 4;
        #pragma unroll
        for (int cb = 0; cb < 8; ++cb) {
            Ps[wave][pr + 0][cb * 16 + l15] = (f16)P[cb].x;
            Ps[wave][pr + 1][cb * 16 + l15] = (f16)P[cb].y;
            Ps[wave][pr + 2][cb * 16 + l15] = (f16)P[cb].z;
            Ps[wave][pr + 3][cb * 16 + l15] = (f16)P[cb].w;
        }
        if (l15 == 0) {
            float4 a4 = {al.x, al.y, al.z, al.w};
            *(float4*)&alpha_s[wave][pr] = a4;
        }
        __syncthreads();   // C: Ps/alpha visible

        // Rescale O by each q-block's alpha (skip when converged)
        float4 alq[8];
        int need = 0;
        #pragma unroll
        for (int qb = 0; qb < 8; ++qb) {
            alq[qb] = *(const float4*)&alpha_s[qb][pr];
            need |= (alq[qb].x != 1.f) | (alq[qb].y != 1.f) |
                    (alq[qb].z != 1.f) | (alq[qb].w != 1.f);
        }
        if (__any(need)) {
            #pragma unroll
            for (int qb = 0; qb < 8; ++qb) {
                f32x4 a = {alq[qb].x, alq[qb].y, alq[qb].z, alq[qb].w};
                acc[qb * 2 + 0] *= a;
                acc[qb * 2 + 1] *= a;
            }
        }

        // PV: 8 q-blocks x 2 d-tiles x 4 kv-quarters; A-frag one b128 each
        #pragma unroll
        for (int qb = 0; qb < 8; ++qb) {
            #pragma unroll
            for (int cbb = 0; cbb < 4; ++cbb) {
                half8 ap = *(const half8*)&Ps[qb][l15][cbb * 32 + quad * 8];
                acc[qb * 2 + 0] = __builtin_amdgcn_mfma_f32_16x16x32_f16(
                    ap, vbf[0][cbb], acc[qb * 2 + 0], 0, 0, 0);
                acc[qb * 2 + 1] = __builtin_amdgcn_mfma_f32_16x16x32_f16(
                    ap, vbf[1][cbb], acc[qb * 2 + 1], 0, 0, 0);
            }
        }
    }

    // Publish l, write m/l partials (this wave's own 16 q rows)
    __syncthreads();
    if (l15 == 0) {
        const int pr = quad * 4;
        float4 lv = {l4.x, l4.y, l4.z, l4.w};
        *(float4*)&l_sh[wave][pr] = lv;
        float mv[4] = {m4.x, m4.y, m4.z, m4.w};
        float lvv[4] = {l4.x, l4.y, l4.z, l4.w};
        #pragma unroll
        for (int r = 0; r < 4; ++r) {
            int n = qw + pr + r;
            mpart[(size_t)(s * Bb + b) * Nn + n] = mv[r];
            lpart[(size_t)(s * Bb + b) * Nn + n] = lvv[r];
        }
    }
    __syncthreads();

    // Normalize + store partial O: 8 q-blocks x this wave's 2 d-tiles
    f16* Ob = Opart + (size_t)(s * Bb + b) * Dd * Nn;
    #pragma unroll
    for (int qb = 0; qb < 8; ++qb) {
        float4 lq = *(const float4*)&l_sh[qb][quad * 4];
        f32x4 inv = {1.f / lq.x, 1.f / lq.y, 1.f / lq.z, 1.f / lq.w};
        #pragma unroll
        for (int dt = 0; dt < 2; ++dt) {
            int d = wave * 32 + dt * 16 + l15;
            f32x4 o = acc[qb * 2 + dt] * inv;
            half4 oh;
            oh[0] = (f16)o.x; oh[1] = (f16)o.y; oh[2] = (f16)o.z; oh[3] = (f16)o.w;
            *(half4*)&Ob[(size_t)d * Nn + q0 + qb * 16 + quad * 4] = oh;
        }
    }
}

// ---------------------------------------------------------------------------
// Kernel 3: combine split partials (exp2 domain).
// ---------------------------------------------------------------------------
__global__ __launch_bounds__(256) void combine(
    const f16* __restrict__ Opart, const float* __restrict__ mpart,
    const float* __restrict__ lpart, float* __restrict__ out)
{
    const int t = threadIdx.x;
    const int n0 = (blockIdx.x * 256 + t) * 8;
    const int d = blockIdx.y, b = blockIdx.z;

    float m[SPLIT][8], l[SPLIT][8];
    #pragma unroll
    for (int s = 0; s < SPLIT; ++s) {
        size_t base = (size_t)(s * Bb + b) * Nn + n0;
        float4 a0 = *(const float4*)&mpart[base];
        float4 a1 = *(const float4*)&mpart[base + 4];
        float4 c0 = *(const float4*)&lpart[base];
        float4 c1 = *(const float4*)&lpart[base + 4];
        m[s][0]=a0.x; m[s][1]=a0.y; m[s][2]=a0.z; m[s][3]=a0.w;
        m[s][4]=a1.x; m[s][5]=a1.y; m[s][6]=a1.z; m[s][7]=a1.w;
        l[s][0]=c0.x; l[s][1]=c0.y; l[s][2]=c0.z; l[s][3]=c0.w;
        l[s][4]=c1.x; l[s][5]=c1.y; l[s][6]=c1.z; l[s][7]=c1.w;
    }
    float w[SPLIT][8];
    #pragma unroll
    for (int jx = 0; jx < 8; ++jx) {
        float M = m[0][jx];
        #pragma unroll
        for (int s = 1; s < SPLIT; ++s) M = fmaxf(M, m[s][jx]);
        float L = 0.f;
        #pragma unroll
        for (int s = 0; s < SPLIT; ++s) {
            float ws = l[s][jx] * __builtin_amdgcn_exp2f(m[s][jx] - M);
            w[s][jx] = ws; L += ws;
        }
        float invL = 1.f / L;
        #pragma unroll
        for (int s = 0; s < SPLIT; ++s) w[s][jx] *= invL;
    }

    float o[8];
    #pragma unroll
    for (int jx = 0; jx < 8; ++jx) o[jx] = 0.f;
    #pragma unroll
    for (int s = 0; s < SPLIT; ++s) {
        half8 h = *(const half8*)&Opart[((size_t)(s * Bb + b) * Dd + d) * Nn + n0];
        #pragma unroll
        for (int jx = 0; jx < 8; ++jx) o[jx] += w[s][jx] * (float)h[jx];
    }
    float* op = out + ((size_t)b * Dd + d) * Nn + n0;
    f32x4 o0 = {o[0], o[1], o[2], o[3]};
    f32x4 o1 = {o[4], o[5], o[6], o[7]};
    *(f32x4*)op = o0;
    *(f32x4*)(op + 4) = o1;
}

extern "C" void kernel_launch(void* const* d_in, const int* in_sizes, int n_in,
                              void* d_out, int out_size, void* d_ws, size_t ws_size,
                              hipStream_t stream) {
    const float* x  = (const float*)d_in[0];
    const float* Wq = (const float*)d_in[1];
    const float* bq = (const float*)d_in[2];
    const float* Wk = (const float*)d_in[3];
    const float* bk = (const float*)d_in[4];
    const float* Wv = (const float*)d_in[5];
    const float* bv = (const float*)d_in[6];
    float* out = (float*)d_out;

    f16* Qh    = (f16*)d_ws;
    f16* Kh    = Qh + (size_t)Bb * Nn * Dd;
    f16* Vth   = Kh + (size_t)Bb * Nn * Dd;
    f16* Wt    = Vth + (size_t)Bb * Nn * Dd;
    f16* Opart = Wt + (size_t)3 * Dd * Dd;
    float* mpart = (float*)(Opart + (size_t)SPLIT * Bb * Dd * Nn);
    float* lpart = mpart + (size_t)SPLIT * Bb * Nn;

    wtrans<<<dim3(16, 3), 256, 0, stream>>>(Wq, Wk, Wv, Wt);
    qkv_mfma<<<dim3(Nn / 64, Bb, 3), 256, 0, stream>>>(
        x, Wt, bq, bk, bv, Qh, Kh, Vth);
    attn_mfma<<<dim3(Nn / BQ, Bb, SPLIT), 512, 0, stream>>>(
        Qh, Kh, Vth, Opart, mpart, lpart);
    combine<<<dim3(Nn / 2048, Dd, Bb), 256, 0, stream>>>(
        Opart, mpart, lpart, out);
}

// Round 13
// 220.643 us; speedup vs baseline: 1.1419x; 1.1419x over previous
//
#include <hip/hip_runtime.h>
#include <math.h>

#define Dd 256
#define Nn 4096
#define Bb 4
#define BQ 128      // q rows per attn block (8 waves x 16 in S phase)
#define BK 128      // kv rows per tile (one barrier-triple per 128 MFMA/wave)
#define SPLIT 2     // KV splits -> grid exactly 256 blocks = 1 round

typedef _Float16 f16;
typedef _Float16 half8 __attribute__((ext_vector_type(8)));
typedef _Float16 half4 __attribute__((ext_vector_type(4)));
typedef float f32x4 __attribute__((ext_vector_type(4)));

#define LOG2E 1.4426950408889634f

// DPP row_ror butterfly over 16-lane rows (VALU pipe, not LDS)
template <int CTRL>
__device__ __forceinline__ float dppf(float x) {
    int r = __builtin_amdgcn_update_dpp(0, __builtin_bit_cast(int, x),
                                        CTRL, 0xF, 0xF, false);
    return __builtin_bit_cast(float, r);
}
__device__ __forceinline__ float red16_max(float x) {
    x = fmaxf(x, dppf<0x128>(x));
    x = fmaxf(x, dppf<0x124>(x));
    x = fmaxf(x, dppf<0x122>(x));
    x = fmaxf(x, dppf<0x121>(x));
    return x;
}
__device__ __forceinline__ float red16_sum(float x) {
    x += dppf<0x128>(x); x += dppf<0x124>(x);
    x += dppf<0x122>(x); x += dppf<0x121>(x);
    return x;
}

// ---------------------------------------------------------------------------
// Kernel 0: W transpose+cast.  Wt[which][d'][d] = (f16) W[d][d']
// ---------------------------------------------------------------------------
__global__ __launch_bounds__(256) void wtrans(
    const float* __restrict__ Wq, const float* __restrict__ Wk,
    const float* __restrict__ Wv, f16* __restrict__ Wt)
{
    __shared__ float ld[64][65];
    const int which = blockIdx.y;
    const float* W = which == 0 ? Wq : (which == 1 ? Wk : Wv);
    const int tr = (blockIdx.x >> 2) * 64;
    const int tc = (blockIdx.x & 3) * 64;
    const int t = threadIdx.x;
    #pragma unroll
    for (int i = 0; i < 16; ++i) {
        int u = t + i * 256, r = u >> 6, c = u & 63;
        ld[r][c] = W[(size_t)(tr + r) * Dd + tc + c];
    }
    __syncthreads();
    f16* Wo = Wt + (size_t)which * Dd * Dd;
    #pragma unroll
    for (int i = 0; i < 16; ++i) {
        int u = t + i * 256, cp = u >> 6, rp = u & 63;
        Wo[(size_t)(tc + cp) * Dd + tr + rp] = (f16)ld[rp][cp];
    }
}

// ---------------------------------------------------------------------------
// Kernel 1: FUSED QKV projection via MFMA (R13).
// One launch computes q,k,v for 64 rows/block. The 135 KB LDS region is
// time-shared: xT tile first (dead after A-frags lift to registers), then
// the ENTIRE 256x256 W (pad 264 -> 2-way banks, free). Per projection:
// [barrier, bulk-stage W from L2, barrier, 64 MFMAs/wave, epilogue].
// 6 barriers/block total (was 16 with 8x less MFMA coverage). x read ONCE.
// 512 threads = 8 waves: row-group g=w&3 (16 rows), col-half h=w>>2 (128).
// Grid (N/64, B) = 256 blocks = 1 round. LDS ~138 KB -> 1 block/CU.
// ---------------------------------------------------------------------------
__global__ __launch_bounds__(512, 1) void qkv_fused(
    const float* __restrict__ x, const f16* __restrict__ Wt,
    const float* __restrict__ bq, const float* __restrict__ bk,
    const float* __restrict__ bv,
    f16* __restrict__ Qh, f16* __restrict__ Kh, f16* __restrict__ Vth)
{
    __shared__ __align__(16) f16 Ws[256][264];   // 135168 B; first 64 rows alias xT
    __shared__ float bs3[3][256];                //   3072 B
    f16 (*xT)[264] = (f16 (*)[264])&Ws[0][0];    // xT[64][264]

    const int t = threadIdx.x;
    const int wave = t >> 6, lane = t & 63, quad = lane >> 4, l15 = lane & 15;
    const int g = wave & 3;        // row group: rows 16g..16g+16
    const int h = wave >> 2;       // col half: d' in [128h, 128h+128)
    const int n0 = blockIdx.x * 64;
    const int b = blockIdx.y;

    if (t < 256) { bs3[0][t] = bq[t]; bs3[1][t] = bk[t]; bs3[2][t] = bv[t]; }

    // Stage xT[n][d] = (f16) x[b][d][n0+n]; 512 threads x 8 float4 reads
    const float* xb = x + (size_t)b * Dd * Nn;
    #pragma unroll
    for (int i = 0; i < 8; ++i) {
        int u = t + i * 512, d = u >> 4, nq = (u & 15) * 4;
        float4 v4 = *(const float4*)&xb[(size_t)d * Nn + n0 + nq];
        xT[nq + 0][d] = (f16)v4.x; xT[nq + 1][d] = (f16)v4.y;
        xT[nq + 2][d] = (f16)v4.z; xT[nq + 3][d] = (f16)v4.w;
    }
    __syncthreads();

    // Lift A-fragments to registers (xT is dead after this + barrier)
    half8 a[8];
    #pragma unroll
    for (int c = 0; c < 8; ++c)
        a[c] = *(const half8*)&xT[16 * g + l15][c * 32 + quad * 8];

    const int nrow = n0 + 16 * g + quad * 4;

    for (int which = 0; which < 3; ++which) {
        __syncthreads();   // A-frag reads (which=0) / prior MFMA reads done

        // Bulk-stage full W^T (256x256 halfs) from L2: 16 b128 per thread
        const f16* Wb = Wt + (size_t)which * Dd * Dd;
        #pragma unroll
        for (int i = 0; i < 16; ++i) {
            int u = t + i * 512;
            int r = u >> 5, c = u & 31;
            *(half8*)&Ws[r][c * 8] = *(const half8*)(Wb + (size_t)r * Dd + c * 8);
        }
        __syncthreads();

        // 64 MFMAs/wave, zero barriers: this wave's 8 col-tiles x 8 k-chunks
        f32x4 acc[8];
        #pragma unroll
        for (int dt = 0; dt < 8; ++dt) acc[dt] = (f32x4){0.f, 0.f, 0.f, 0.f};
        #pragma unroll
        for (int c = 0; c < 8; ++c) {
            #pragma unroll
            for (int dt = 0; dt < 8; ++dt) {
                half8 bfr = *(const half8*)&Ws[h * 128 + dt * 16 + l15][c * 32 + quad * 8];
                acc[dt] = __builtin_amdgcn_mfma_f32_16x16x32_f16(a[c], bfr, acc[dt], 0, 0, 0);
            }
        }

        // Epilogue
        if (which < 2) {
            f16* O = (which == 0 ? Qh : Kh) + ((size_t)b * Nn + nrow) * Dd;
            #pragma unroll
            for (int dt = 0; dt < 8; ++dt) {
                int col = h * 128 + dt * 16 + l15;
                float bvv = bs3[which][col];
                #pragma unroll
                for (int r = 0; r < 4; ++r)
                    O[(size_t)r * Dd + col] = (f16)(acc[dt][r] + bvv);
            }
        } else {
            f16* O = Vth + (size_t)b * Dd * Nn;
            #pragma unroll
            for (int dt = 0; dt < 8; ++dt) {
                int col = h * 128 + dt * 16 + l15;
                float bvv = bs3[2][col];
                half4 o;
                #pragma unroll
                for (int r = 0; r < 4; ++r) o[r] = (f16)(acc[dt][r] + bvv);
                *(half4*)&O[(size_t)col * Nn + nrow] = o;
            }
        }
    }
}

// ---------------------------------------------------------------------------
// Kernel 2: MFMA flash attention (byte-identical to the R11 winner). BK=128:
// 3 barriers per 128 MFMA/wave (16 iterations). BQ=128, 512 threads,
// SPLIT=2 -> grid 256 blocks = 1 round. Wave-split-D PV (32 d-cols/wave).
// ---------------------------------------------------------------------------
__global__ __launch_bounds__(512, 2) void attn_mfma(
    const f16* __restrict__ Qh, const f16* __restrict__ Kh,
    const f16* __restrict__ Vth, f16* __restrict__ Opart,
    float* __restrict__ mpart, float* __restrict__ lpart)
{
    __shared__ f16 Ks[BK][264];       // 67584 B  K[kv][d], pad 8
    __shared__ f16 Ps[8][16][136];    // 34816 B  P[qb][q][kv 0..127], pad 8
    __shared__ float alpha_s[8][16];  //   512 B
    __shared__ float l_sh[8][16];     //   512 B

    const int t    = threadIdx.x;
    const int wave = t >> 6, lane = t & 63;
    const int quad = lane >> 4, l15 = lane & 15;
    const int b    = blockIdx.y;
    const int s    = blockIdx.z;
    const int q0   = blockIdx.x * BQ;
    const int qw   = q0 + wave * 16;       // this wave's S-phase q rows
    const int kv0  = s * (Nn / SPLIT);

    // Q A-fragments, pre-scaled by log2(e)
    half8 qf[8];
    const f16* Qrow = Qh + ((size_t)b * Nn + qw + l15) * Dd + quad * 8;
    #pragma unroll
    for (int c = 0; c < 8; ++c) {
        qf[c] = *(const half8*)(Qrow + c * 32);
        qf[c] = qf[c] * (f16)LOG2E;
    }

    // acc[qb*2+dt]: q-block qb (0..7), d-cols 32*wave + dt*16 + l15 (dt 0..1)
    f32x4 acc[16];
    #pragma unroll
    for (int n = 0; n < 16; ++n) acc[n] = (f32x4){0.f, 0.f, 0.f, 0.f};
    f32x4 m4 = {-1e30f, -1e30f, -1e30f, -1e30f};
    f32x4 l4 = {0.f, 0.f, 0.f, 0.f};

    const f16* Kb   = Kh + (size_t)b * Nn * Dd;
    const f16* Vrow = Vth + (size_t)b * Dd * Nn
                    + (size_t)(wave * 32 + l15) * Nn + quad * 8;

    for (int k0 = kv0; k0 < kv0 + Nn / SPLIT; k0 += BK) {
        // Iter-top V loads: 2 d-tiles x 4 kv-quarters (full 128B V lines)
        half8 vbf[2][4];   // [dt][kv quarter]
        #pragma unroll
        for (int dt = 0; dt < 2; ++dt) {
            #pragma unroll
            for (int cbb = 0; cbb < 4; ++cbb)
                vbf[dt][cbb] = *(const half8*)(Vrow + (size_t)dt * 16 * Nn + k0 + cbb * 32);
        }

        __syncthreads();   // A: prior readers of Ks/Ps done

        // Stage K tile: 128 rows x 512 B = 64 KB; 8 x b128 per thread
        #pragma unroll
        for (int i = 0; i < 8; ++i) {
            int u = t + i * 512;
            int r = u >> 5, c = u & 31;
            *(half8*)&Ks[r][c * 8] =
                *(const half8*)(Kb + (size_t)(k0 + r) * Dd + c * 8);
        }
        __syncthreads();   // B: K visible

        // S = Q K^T (log2 domain), eight 16x16 col-blocks (kv 0..127)
        f32x4 S[8];
        #pragma unroll
        for (int cb = 0; cb < 8; ++cb) S[cb] = (f32x4){0.f, 0.f, 0.f, 0.f};
        #pragma unroll
        for (int c = 0; c < 8; ++c) {
            #pragma unroll
            for (int cb = 0; cb < 8; ++cb) {
                half8 kb = *(const half8*)&Ks[cb * 16 + l15][c * 32 + quad * 8];
                S[cb] = __builtin_amdgcn_mfma_f32_16x16x32_f16(qf[c], kb, S[cb], 0, 0, 0);
            }
        }

        // Online softmax (exp2 domain), DPP reductions over 16 lanes
        f32x4 tmax = S[0];
        #pragma unroll
        for (int cb = 1; cb < 8; ++cb) {
            tmax.x = fmaxf(tmax.x, S[cb].x); tmax.y = fmaxf(tmax.y, S[cb].y);
            tmax.z = fmaxf(tmax.z, S[cb].z); tmax.w = fmaxf(tmax.w, S[cb].w);
        }
        tmax.x = red16_max(tmax.x); tmax.y = red16_max(tmax.y);
        tmax.z = red16_max(tmax.z); tmax.w = red16_max(tmax.w);
        f32x4 newm;
        newm.x = fmaxf(m4.x, tmax.x); newm.y = fmaxf(m4.y, tmax.y);
        newm.z = fmaxf(m4.z, tmax.z); newm.w = fmaxf(m4.w, tmax.w);
        f32x4 al;
        al.x = __builtin_amdgcn_exp2f(m4.x - newm.x);
        al.y = __builtin_amdgcn_exp2f(m4.y - newm.y);
        al.z = __builtin_amdgcn_exp2f(m4.z - newm.z);
        al.w = __builtin_amdgcn_exp2f(m4.w - newm.w);
        f32x4 P[8];
        #pragma unroll
        for (int cb = 0; cb < 8; ++cb) {
            P[cb].x = __builtin_amdgcn_exp2f(S[cb].x - newm.x);
            P[cb].y = __builtin_amdgcn_exp2f(S[cb].y - newm.y);
            P[cb].z = __builtin_amdgcn_exp2f(S[cb].z - newm.z);
            P[cb].w = __builtin_amdgcn_exp2f(S[cb].w - newm.w);
        }
        f32x4 rsum = P[0];
        #pragma unroll
        for (int cb = 1; cb < 8; ++cb) rsum += P[cb];
        rsum.x = red16_sum(rsum.x); rsum.y = red16_sum(rsum.y);
        rsum.z = red16_sum(rsum.z); rsum.w = red16_sum(rsum.w);
        l4 = l4 * al + rsum;
        m4 = newm;

        // Publish P (f16) and alpha
        const int pr = quad * 4;
        #pragma unroll
        for (int cb = 0; cb < 8; ++cb) {
            Ps[wave][pr + 0][cb * 16 + l15] = (f16)P[cb].x;
            Ps[wave][pr + 1][cb * 16 + l15] = (f16)P[cb].y;
            Ps[wave][pr + 2][cb * 16 + l15] = (f16)P[cb].z;
            Ps[wave][pr + 3][cb * 16 + l15] = (f16)P[cb].w;
        }
        if (l15 == 0) {
            float4 a4 = {al.x, al.y, al.z, al.w};
            *(float4*)&alpha_s[wave][pr] = a4;
        }
        __syncthreads();   // C: Ps/alpha visible

        // Rescale O by each q-block's alpha (skip when converged)
        float4 alq[8];
        int need = 0;
        #pragma unroll
        for (int qb = 0; qb < 8; ++qb) {
            alq[qb] = *(const float4*)&alpha_s[qb][pr];
            need |= (alq[qb].x != 1.f) | (alq[qb].y != 1.f) |
                    (alq[qb].z != 1.f) | (alq[qb].w != 1.f);
        }
        if (__any(need)) {
            #pragma unroll
            for (int qb = 0; qb < 8; ++qb) {
                f32x4 a = {alq[qb].x, alq[qb].y, alq[qb].z, alq[qb].w};
                acc[qb * 2 + 0] *= a;
                acc[qb * 2 + 1] *= a;
            }
        }

        // PV: 8 q-blocks x 2 d-tiles x 4 kv-quarters; A-frag one b128 each
        #pragma unroll
        for (int qb = 0; qb < 8; ++qb) {
            #pragma unroll
            for (int cbb = 0; cbb < 4; ++cbb) {
                half8 ap = *(const half8*)&Ps[qb][l15][cbb * 32 + quad * 8];
                acc[qb * 2 + 0] = __builtin_amdgcn_mfma_f32_16x16x32_f16(
                    ap, vbf[0][cbb], acc[qb * 2 + 0], 0, 0, 0);
                acc[qb * 2 + 1] = __builtin_amdgcn_mfma_f32_16x16x32_f16(
                    ap, vbf[1][cbb], acc[qb * 2 + 1], 0, 0, 0);
            }
        }
    }

    // Publish l, write m/l partials (this wave's own 16 q rows)
    __syncthreads();
    if (l15 == 0) {
        const int pr = quad * 4;
        float4 lv = {l4.x, l4.y, l4.z, l4.w};
        *(float4*)&l_sh[wave][pr] = lv;
        float mv[4] = {m4.x, m4.y, m4.z, m4.w};
        float lvv[4] = {l4.x, l4.y, l4.z, l4.w};
        #pragma unroll
        for (int r = 0; r < 4; ++r) {
            int n = qw + pr + r;
            mpart[(size_t)(s * Bb + b) * Nn + n] = mv[r];
            lpart[(size_t)(s * Bb + b) * Nn + n] = lvv[r];
        }
    }
    __syncthreads();

    // Normalize + store partial O: 8 q-blocks x this wave's 2 d-tiles
    f16* Ob = Opart + (size_t)(s * Bb + b) * Dd * Nn;
    #pragma unroll
    for (int qb = 0; qb < 8; ++qb) {
        float4 lq = *(const float4*)&l_sh[qb][quad * 4];
        f32x4 inv = {1.f / lq.x, 1.f / lq.y, 1.f / lq.z, 1.f / lq.w};
        #pragma unroll
        for (int dt = 0; dt < 2; ++dt) {
            int d = wave * 32 + dt * 16 + l15;
            f32x4 o = acc[qb * 2 + dt] * inv;
            half4 oh;
            oh[0] = (f16)o.x; oh[1] = (f16)o.y; oh[2] = (f16)o.z; oh[3] = (f16)o.w;
            *(half4*)&Ob[(size_t)d * Nn + q0 + qb * 16 + quad * 4] = oh;
        }
    }
}

// ---------------------------------------------------------------------------
// Kernel 3: combine split partials (exp2 domain).
// ---------------------------------------------------------------------------
__global__ __launch_bounds__(256) void combine(
    const f16* __restrict__ Opart, const float* __restrict__ mpart,
    const float* __restrict__ lpart, float* __restrict__ out)
{
    const int t = threadIdx.x;
    const int n0 = (blockIdx.x * 256 + t) * 8;
    const int d = blockIdx.y, b = blockIdx.z;

    float m[SPLIT][8], l[SPLIT][8];
    #pragma unroll
    for (int s = 0; s < SPLIT; ++s) {
        size_t base = (size_t)(s * Bb + b) * Nn + n0;
        float4 a0 = *(const float4*)&mpart[base];
        float4 a1 = *(const float4*)&mpart[base + 4];
        float4 c0 = *(const float4*)&lpart[base];
        float4 c1 = *(const float4*)&lpart[base + 4];
        m[s][0]=a0.x; m[s][1]=a0.y; m[s][2]=a0.z; m[s][3]=a0.w;
        m[s][4]=a1.x; m[s][5]=a1.y; m[s][6]=a1.z; m[s][7]=a1.w;
        l[s][0]=c0.x; l[s][1]=c0.y; l[s][2]=c0.z; l[s][3]=c0.w;
        l[s][4]=c1.x; l[s][5]=c1.y; l[s][6]=c1.z; l[s][7]=c1.w;
    }
    float w[SPLIT][8];
    #pragma unroll
    for (int jx = 0; jx < 8; ++jx) {
        float M = m[0][jx];
        #pragma unroll
        for (int s = 1; s < SPLIT; ++s) M = fmaxf(M, m[s][jx]);
        float L = 0.f;
        #pragma unroll
        for (int s = 0; s < SPLIT; ++s) {
            float ws = l[s][jx] * __builtin_amdgcn_exp2f(m[s][jx] - M);
            w[s][jx] = ws; L += ws;
        }
        float invL = 1.f / L;
        #pragma unroll
        for (int s = 0; s < SPLIT; ++s) w[s][jx] *= invL;
    }

    float o[8];
    #pragma unroll
    for (int jx = 0; jx < 8; ++jx) o[jx] = 0.f;
    #pragma unroll
    for (int s = 0; s < SPLIT; ++s) {
        half8 h = *(const half8*)&Opart[((size_t)(s * Bb + b) * Dd + d) * Nn + n0];
        #pragma unroll
        for (int jx = 0; jx < 8; ++jx) o[jx] += w[s][jx] * (float)h[jx];
    }
    float* op = out + ((size_t)b * Dd + d) * Nn + n0;
    f32x4 o0 = {o[0], o[1], o[2], o[3]};
    f32x4 o1 = {o[4], o[5], o[6], o[7]};
    *(f32x4*)op = o0;
    *(f32x4*)(op + 4) = o1;
}

extern "C" void kernel_launch(void* const* d_in, const int* in_sizes, int n_in,
                              void* d_out, int out_size, void* d_ws, size_t ws_size,
                              hipStream_t stream) {
    const float* x  = (const float*)d_in[0];
    const float* Wq = (const float*)d_in[1];
    const float* bq = (const float*)d_in[2];
    const float* Wk = (const float*)d_in[3];
    const float* bk = (const float*)d_in[4];
    const float* Wv = (const float*)d_in[5];
    const float* bv = (const float*)d_in[6];
    float* out = (float*)d_out;

    f16* Qh    = (f16*)d_ws;
    f16* Kh    = Qh + (size_t)Bb * Nn * Dd;
    f16* Vth   = Kh + (size_t)Bb * Nn * Dd;
    f16* Wt    = Vth + (size_t)Bb * Nn * Dd;
    f16* Opart = Wt + (size_t)3 * Dd * Dd;
    float* mpart = (float*)(Opart + (size_t)SPLIT * Bb * Dd * Nn);
    float* lpart = mpart + (size_t)SPLIT * Bb * Nn;

    wtrans<<<dim3(16, 3), 256, 0, stream>>>(Wq, Wk, Wv, Wt);
    qkv_fused<<<dim3(Nn / 64, Bb), 512, 0, stream>>>(
        x, Wt, bq, bk, bv, Qh, Kh, Vth);
    attn_mfma<<<dim3(Nn / BQ, Bb, SPLIT), 512, 0, stream>>>(
        Qh, Kh, Vth, Opart, mpart, lpart);
    combine<<<dim3(Nn / 2048, Dd, Bb), 256, 0, stream>>>(
        Opart, mpart, lpart, out);
}